// Round 7
// baseline (177.083 us; speedup 1.0000x reference)
//
#include <hip/hip_runtime.h>
#include <hip/hip_bf16.h>

typedef __attribute__((ext_vector_type(8))) short short8;
typedef __attribute__((ext_vector_type(4))) short bf16x4;
typedef __attribute__((ext_vector_type(4))) float floatx4;

#define T_SEQ 2048
#define NH    16
#define HD    64
#define QSCALE 0.18033688f   // 0.125 * log2(e): folded into Q at GEMM1 epilogue

// v_mfma_f32_16x16x16_bf16 (4 bf16/lane A,B; 4 f32/lane C)
#define MFMA16(a, b, c) __builtin_amdgcn_mfma_f32_16x16x16bf16_1k(a, b, c, 0, 0, 0)
#define MFMA32(a, b, c) __builtin_amdgcn_mfma_f32_16x16x32_bf16(a, b, c, 0, 0, 0)

__device__ __forceinline__ ushort f2bf(float f) {
    union { float f; unsigned u; } un; un.f = f;
    unsigned r = un.u + 0x7fff + ((un.u >> 16) & 1);
    return (ushort)(r >> 16);
}
__device__ __forceinline__ unsigned pkbf(float a, float b) {   // packed cvt (1 inst)
    __hip_bfloat162 t = __float22bfloat162_rn(float2{a, b});
    return *reinterpret_cast<unsigned*>(&t);
}

typedef const __attribute__((address_space(1))) unsigned int* gp1_t;
typedef __attribute__((address_space(3))) unsigned int* lp3_t;
__device__ __forceinline__ void gl_lds16(const ushort* g, ushort* l) {
    __builtin_amdgcn_global_load_lds((gp1_t)g, (lp3_t)l, 16, 0, 0);
}

// -------- fused prep: W transposes (fp32->bf16) + x convert ----------------
__global__ void prep_kernel(const float* __restrict__ Wqkv, const float* __restrict__ Wout,
                            const float* __restrict__ x, ushort* __restrict__ wt_qkv,
                            ushort* __restrict__ wt_out, ushort* __restrict__ x_bf) {
    __shared__ ushort tile[32][33];
    const int bid = blockIdx.x;
    if (bid >= 4096) {   // convert path
        size_t i = ((size_t)(bid - 4096) * 256 + threadIdx.x) * 8;
        float4 f0 = *(const float4*)(x + i);
        float4 f1 = *(const float4*)(x + i + 4);
        short8 v;
        v[0] = (short)f2bf(f0.x); v[1] = (short)f2bf(f0.y);
        v[2] = (short)f2bf(f0.z); v[3] = (short)f2bf(f0.w);
        v[4] = (short)f2bf(f1.x); v[5] = (short)f2bf(f1.y);
        v[6] = (short)f2bf(f1.z); v[7] = (short)f2bf(f1.w);
        *(short8*)(x_bf + i) = v;
        return;
    }
    const float* in; ushort* out; int R, C, gx, gy;
    if (bid < 3072) { in = Wqkv; out = wt_qkv; R = 1024; C = 3072; gx = bid % 96; gy = bid / 96; }
    else            { int t = bid - 3072; in = Wout; out = wt_out; R = 1024; C = 1024; gx = t & 31; gy = t >> 5; }
    const int tx = threadIdx.x & 31, ty = threadIdx.x >> 5;
    const int bx = gx * 32, by = gy * 32;
    #pragma unroll
    for (int i = ty; i < 32; i += 8)
        tile[i][tx] = f2bf(in[(size_t)(by + i) * C + bx + tx]);
    __syncthreads();
    #pragma unroll
    for (int i = ty; i < 32; i += 8)
        out[(size_t)(bx + i) * R + by + tx] = tile[tx][i];
}

// ---------------- GEMM: C[M][N] = A[M][K] * Bt[N][K]^T  (bf16 MFMA, fp32 acc) --
// Tile 128 x BN (BN=128 for GEMM1, BN=64 for GEMM2 -> grid 512 = 2 blocks/CU so
// barrier drains overlap with the co-resident block). BK=64. XOR-swizzled
// staging (pre-swizzled global source, linear gl_lds dest). XCD bijective swizzle.
// EPI==0 epilogues (Q/K scatter and V transpose) both go through LDS for
// coalesced 16B stores.
template <int EPI, int BN>
__global__ __launch_bounds__(256, 2)
void gemm_bt(const ushort* __restrict__ A, const ushort* __restrict__ Bt,
             void* __restrict__ O0, ushort* __restrict__ O1, ushort* __restrict__ O2,
             int M, int N, int K) {
    constexpr int NJ = BN / 32;                    // j-frags per wave (BN/2/16)
    constexpr int NB = (BN * 8) / 256;             // B staging chunks per thread
    __shared__ __align__(16) ushort smem[8192 + BN * 64];   // As | Bs; epilogue reuse
    ushort* As = smem;
    ushort* Bs = smem + 8192;
    const int tid  = threadIdx.x;
    const int wave = tid >> 6, lane = tid & 63;
    const int quad = lane >> 4, l16 = lane & 15;
    const int wm = (wave >> 1) * 64, wn = (wave & 1) * (BN / 2);

    const int nwg = gridDim.x * gridDim.y;            // multiple of 8
    const int lid = blockIdx.y * gridDim.x + blockIdx.x;
    const int cpx = nwg >> 3;
    const int swz = (lid & 7) * cpx + (lid >> 3);
    const int m0 = (swz / gridDim.y) * 128;
    const int n0 = (swz % gridDim.y) * BN;

    // staging pointers: A 1024 chunks (4/thread), B BN*8 chunks (NB/thread)
    const ushort* aP[4];
    const ushort* bP[NB];
    #pragma unroll
    for (int j = 0; j < 4; j++) {
        int c = tid + j * 256;
        int r = c >> 3;
        int g = ((c & 7) ^ (r & 7)) * 8;
        aP[j] = A + (size_t)(m0 + r) * K + g;
    }
    #pragma unroll
    for (int j = 0; j < NB; j++) {
        int c = tid + j * 256;
        int r = c >> 3;
        int g = ((c & 7) ^ (r & 7)) * 8;
        bP[j] = Bt + (size_t)(n0 + r) * K + g;
    }

    floatx4 acc[4][NJ];
    #pragma unroll
    for (int i = 0; i < 4; i++)
        #pragma unroll
        for (int j = 0; j < NJ; j++)
            acc[i][j] = (floatx4){0.f, 0.f, 0.f, 0.f};

    const int xsw = l16 & 7;

    for (int k0 = 0; k0 < K; k0 += 64) {
        __syncthreads();
        #pragma unroll
        for (int j = 0; j < 4; j++)  gl_lds16(aP[j] + k0, &As[(tid + j * 256) * 8]);
        #pragma unroll
        for (int j = 0; j < NB; j++) gl_lds16(bP[j] + k0, &Bs[(tid + j * 256) * 8]);
        __syncthreads();
        #pragma unroll
        for (int kk = 0; kk < 2; kk++) {
            short8 af[4], bf[NJ];
            #pragma unroll
            for (int i = 0; i < 4; i++)
                af[i] = *(const short8*)(&As[(wm + i * 16 + l16) * 64 + ((kk * 4 + quad) ^ xsw) * 8]);
            #pragma unroll
            for (int j = 0; j < NJ; j++)
                bf[j] = *(const short8*)(&Bs[(wn + j * 16 + l16) * 64 + ((kk * 4 + quad) ^ xsw) * 8]);
            #pragma unroll
            for (int i = 0; i < 4; i++)
                #pragma unroll
                for (int j = 0; j < NJ; j++)
                    acc[i][j] = MFMA32(af[i], bf[j], acc[i][j]);
        }
    }

    if constexpr (EPI == 0) {
        const int b = m0 >> 11;
        const int t0 = m0 & 2047;
        if (n0 >= 2048) {
            // pure V block: LDS transpose -> coalesced 16B stores into vT[B,H,hd,T]
            const int head0 = (n0 - 2048) >> 6;
            __syncthreads();
            #pragma unroll
            for (int nh = 0; nh < 2; nh++) {
                if ((wave & 1) == nh) {
                    #pragma unroll
                    for (int j = 0; j < NJ; j++)
                        #pragma unroll
                        for (int i = 0; i < 4; i++) {
                            int nl = j * 16 + l16;
                            int mB = wm + i * 16 + quad * 4;
                            *(unsigned*)(&smem[nl * 136 + mB])     = pkbf(acc[i][j][0], acc[i][j][1]);
                            *(unsigned*)(&smem[nl * 136 + mB + 2]) = pkbf(acc[i][j][2], acc[i][j][3]);
                        }
                }
                __syncthreads();
                #pragma unroll
                for (int cc = 0; cc < 4; cc++) {
                    int c = cc * 256 + tid;
                    int row = c >> 4, mcol = (c & 15) * 8;
                    uint4 v = *(const uint4*)(&smem[row * 136 + mcol]);
                    *(uint4*)(&O2[((size_t)(b * NH + head0 + nh) * HD + row) * T_SEQ + t0 + mcol]) = v;
                }
                __syncthreads();
            }
        } else {
            // Q/K block: LDS transpose -> coalesced 16B stores into [B,H,T,hd].
            // Per 64-col half (= one head): owner waves (wn==nh*64) write bf16
            // into a padded [128][72] tile; all threads store 4x uint4 rows.
            __syncthreads();
            #pragma unroll
            for (int nh = 0; nh < 2; nh++) {
                const int nn = n0 + nh * 64;
                const int part = nn >> 10;                 // 0 = Q, 1 = K
                const int head = (nn & 1023) >> 6;
                ushort* OP = (part == 0) ? (ushort*)O0 : O1;
                const float qs = (part == 0) ? QSCALE : 1.0f;
                if ((wave & 1) == nh) {
                    #pragma unroll
                    for (int i = 0; i < 4; i++)
                        #pragma unroll
                        for (int j = 0; j < NJ; j++) {
                            const int col = j * 16 + l16;
                            const int rowb = wm + i * 16 + quad * 4;
                            #pragma unroll
                            for (int r = 0; r < 4; r++)
                                smem[(rowb + r) * 72 + col] = f2bf(acc[i][j][r] * qs);
                        }
                }
                __syncthreads();
                const size_t obase = ((size_t)(b * NH + head)) * T_SEQ + t0;
                #pragma unroll
                for (int cc = 0; cc < 4; cc++) {
                    int c = cc * 256 + tid;
                    int row = c >> 3, col8 = (c & 7) * 8;
                    uint4 v = *(const uint4*)(&smem[row * 72 + col8]);
                    *(uint4*)(&OP[(obase + row) * HD + col8]) = v;
                }
                __syncthreads();
            }
        }
        return;
    } else {
        #pragma unroll
        for (int i = 0; i < 4; i++)
            #pragma unroll
            for (int j = 0; j < NJ; j++)
                #pragma unroll
                for (int r = 0; r < 4; r++) {
                    int m = m0 + wm + i * 16 + quad * 4 + r;
                    int n = n0 + wn + j * 16 + l16;
                    ((float*)O0)[(size_t)m * N + n] = acc[i][j][r];
                }
    }
}

// -------- online-softmax over one 64-key S^T tile: ALL-DEFERRED version --------
// No cross-lane ops on the common path: per-lane max vote (T13, thr=8 in log2
// domain); lane-local partial l (rescaled by alpha like O, reduced once in the
// epilogue). Cross-lane max (2 shfl) only on the rare rescale-trigger path.
__device__ __forceinline__ void softmax_step(floatx4 s[4], float& mst, float& ll,
                                             floatx4 o[4], bf16x4 pf[4]) {
    float t0 = fmaxf(fmaxf(s[0][0], s[0][1]), fmaxf(s[0][2], s[0][3]));
    float t1 = fmaxf(fmaxf(s[1][0], s[1][1]), fmaxf(s[1][2], s[1][3]));
    float t2 = fmaxf(fmaxf(s[2][0], s[2][1]), fmaxf(s[2][2], s[2][3]));
    float t3 = fmaxf(fmaxf(s[3][0], s[3][1]), fmaxf(s[3][2], s[3][3]));
    float t  = fmaxf(fmaxf(t0, t1), fmaxf(t2, t3));
    if (!__all(t - mst <= 8.0f)) {      // rare: some lane's max really grew
        t = fmaxf(t, __shfl_xor(t, 16));
        t = fmaxf(t, __shfl_xor(t, 32));
        float mnew  = fmaxf(mst, t);
        float alpha = exp2f(mst - mnew);
        mst = mnew;
        ll  *= alpha;
        #pragma unroll
        for (int db = 0; db < 4; db++)
            #pragma unroll
            for (int r = 0; r < 4; r++) o[db][r] *= alpha;
    }
    #pragma unroll
    for (int j = 0; j < 4; j++) {
        float p0 = exp2f(s[j][0] - mst);
        float p1 = exp2f(s[j][1] - mst);
        float p2 = exp2f(s[j][2] - mst);
        float p3 = exp2f(s[j][3] - mst);
        ll += (p0 + p1) + (p2 + p3);
        union { bf16x4 v; unsigned u[2]; } pu;
        pu.u[0] = pkbf(p0, p1);
        pu.u[1] = pkbf(p2, p3);
        pf[j] = pu.v;
    }
}

// ---------------- flash attention, S^T formulation, folded q-tile pairs -------
// Block = (bh, pair): q-tiles {p, 31-p}, uniform 33 subtile-computes per block.
// R3 schedule (best measured): both 64-key subtiles of a staged 128-key chunk
// run as concurrent chains; QK MFMAs up front, softmax(next) adjacent to
// PV(prev). One barrier per 128 keys. All-deferred softmax.
__global__ __launch_bounds__(256, 2)
void attn_kernel(const ushort* __restrict__ Q, const ushort* __restrict__ Kk,
                 const ushort* __restrict__ Vt, ushort* __restrict__ Oout) {
    __shared__ __align__(16) ushort Ks[2][128 * 64];   // [key][d]
    __shared__ __align__(16) ushort Vs[2][64 * 128];   // [d][key]
    const int tid  = threadIdx.x;
    const int wave = tid >> 6, lane = tid & 63;
    const int quad = lane >> 4, l16 = lane & 15;
    const int idx = blockIdx.x;
    const int bh = idx & 31;
    const int jp = idx >> 5;                         // 0..15
    const int p  = (jp < 8) ? jp : (15 - (jp - 8));  // co-res {jp,jp+8} -> {p,15-p}
    const int qtA = p, qtB = 31 - p;                 // qtA <= 15 < 16 <= qtB
    const int b = bh >> 4, h = bh & 15;

    const ushort* qp = Q  + (size_t)bh * T_SEQ * HD;
    const ushort* kp = Kk + (size_t)bh * T_SEQ * HD;
    const ushort* vp = Vt + (size_t)bh * HD * T_SEQ;

    const int q0A = qtA * 64 + wave * 16;
    const int q0B = qtB * 64 + wave * 16;

    short8 qfA[2], qfB[2];                   // B-operand: n=q=l16, k=d
    #pragma unroll
    for (int kb = 0; kb < 2; kb++) {
        qfA[kb] = *(const short8*)(qp + (size_t)(q0A + l16) * HD + kb * 32 + quad * 8);
        qfB[kb] = *(const short8*)(qp + (size_t)(q0B + l16) * HD + kb * 32 + quad * 8);
    }

    floatx4 oA[4], oB[4];                    // O^T accum: d = db*16+quad*4+r, q = l16
    #pragma unroll
    for (int db = 0; db < 4; db++) {
        oA[db] = (floatx4){0.f, 0.f, 0.f, 0.f};
        oB[db] = (floatx4){0.f, 0.f, 0.f, 0.f};
    }
    float mA = -1e30f, llA = 0.f, mB = -1e30f, llB = 0.f;

    // staging offsets: 1024 chunks of 16B per operand per 128-key chunk;
    // thread covers c = tid + j*256. Pre-swizzled global source so the
    // (linear) gl_lds destination yields XOR-swizzled LDS rows.
    int koff[4], voff[4];
    #pragma unroll
    for (int j = 0; j < 4; j++) {
        int c = tid + j * 256;
        int kr = c >> 3;                       // 0..127 (key)
        koff[j] = kr * HD + (((c & 7) ^ (kr & 7)) * 8);
        int vr = c >> 4;                       // 0..63 (d)
        voff[j] = vr * T_SEQ + ((((c & 15) ^ (vr & 7))) * 8);
    }

#define STAGE(BUF, I)                                                            \
    {                                                                            \
        const ushort* kg = kp + (size_t)(I) * 128 * HD;                          \
        const ushort* vg = vp + (I) * 128;                                       \
        gl_lds16(kg + koff[0], &Ks[BUF][(tid      ) * 8]);                       \
        gl_lds16(kg + koff[1], &Ks[BUF][(tid + 256) * 8]);                       \
        gl_lds16(kg + koff[2], &Ks[BUF][(tid + 512) * 8]);                       \
        gl_lds16(kg + koff[3], &Ks[BUF][(tid + 768) * 8]);                       \
        gl_lds16(vg + voff[0], &Vs[BUF][(tid      ) * 8]);                       \
        gl_lds16(vg + voff[1], &Vs[BUF][(tid + 256) * 8]);                       \
        gl_lds16(vg + voff[2], &Vs[BUF][(tid + 512) * 8]);                       \
        gl_lds16(vg + voff[3], &Vs[BUF][(tid + 768) * 8]);                       \
    }

    // hoisted LDS fragment addresses (ushort indices)
    const int xsw = (l16 & 7), qh = quad >> 1, ql = quad & 1;
    const int ka0 = l16 * 64 + ((quad ^ xsw) * 8);          // K: row stride 64
    const int ka1 = l16 * 64 + (((4 + quad) ^ xsw) * 8);
    int va[4];                                               // V: row stride 128
    #pragma unroll
    for (int jj = 0; jj < 4; jj++)
        va[jj] = l16 * 128 + (((2 * jj + qh) ^ xsw) * 8) + ql * 4;

#define ZS(S) { _Pragma("unroll") for (int z = 0; z < 4; z++) S[z] = (floatx4){0.f, 0.f, 0.f, 0.f}; }

// dual QK: one kf LDS read feeds both tiles' accumulations
#define QKD(SB, SA, BUF, ST)                                                     \
    {                                                                            \
        _Pragma("unroll")                                                        \
        for (int jj = 0; jj < 4; jj++) {                                         \
            short8 kf = *(const short8*)(&Ks[BUF][(ST) * 4096 + jj * 1024 + ka0]); \
            SB[jj] = MFMA32(kf, qfB[0], SB[jj]);                                 \
            SA[jj] = MFMA32(kf, qfA[0], SA[jj]);                                 \
        }                                                                        \
        _Pragma("unroll")                                                        \
        for (int jj = 0; jj < 4; jj++) {                                         \
            short8 kf = *(const short8*)(&Ks[BUF][(ST) * 4096 + jj * 1024 + ka1]); \
            SB[jj] = MFMA32(kf, qfB[1], SB[jj]);                                 \
            SA[jj] = MFMA32(kf, qfA[1], SA[jj]);                                 \
        }                                                                        \
    }

#define QK1(SB, BUF, ST)                                                         \
    {                                                                            \
        _Pragma("unroll")                                                        \
        for (int jj = 0; jj < 4; jj++) {                                         \
            short8 kf = *(const short8*)(&Ks[BUF][(ST) * 4096 + jj * 1024 + ka0]); \
            SB[jj] = MFMA32(kf, qfB[0], SB[jj]);                                 \
        }                                                                        \
        _Pragma("unroll")                                                        \
        for (int jj = 0; jj < 4; jj++) {                                         \
            short8 kf = *(const short8*)(&Ks[BUF][(ST) * 4096 + jj * 1024 + ka1]); \
            SB[jj] = MFMA32(kf, qfB[1], SB[jj]);                                 \
        }                                                                        \
    }

#define MASKD(S)                                                                 \
    {                                                                            \
        _Pragma("unroll")                                                        \
        for (int jj = 0; jj < 4; jj++)                                           \
            _Pragma("unroll")                                                    \
            for (int rr = 0; rr < 4; rr++)                                       \
                if (jj * 16 + quad * 4 + rr > wave * 16 + l16) S[jj][rr] = -1e30f; \
    }

#define PVG(O, PF, BUF, ST)                                                      \
    {                                                                            \
        _Pragma("unroll")                                                        \
        for (int jj = 0; jj < 4; jj++)                                           \
            _Pragma("unroll")                                                    \
            for (int db = 0; db < 4; db++) {                                     \
                bf16x4 vf = *(const bf16x4*)(&Vs[BUF][va[jj] + (ST) * 64 + db * 2048]); \
                O[db] = MFMA16(vf, PF[jj], O[db]);                               \
            }                                                                    \
    }

// one 128-key iteration: barrier (drains prefetch), prefetch next chunk,
// then both 64-key subtiles as interleaved chains:
//   QK(all) -> smB0 -> [PV B0 || smB1] -> [PV B1 || smA0] -> [PV A0 || smA1] -> PV A1
#define ITER(BUF, I)                                                             \
    {                                                                            \
        __syncthreads();                                                         \
        if ((I) + 1 < NT) STAGE((BUF) ^ 1, (I) + 1)                              \
        const int kt0 = 2 * (I), kt1 = kt0 + 1;                                  \
        const bool v1 = (kt1 <= qtB);                                            \
        const bool a0 = (kt0 <= qtA), a1 = (kt1 <= qtA);                         \
        floatx4 sB0[4], sB1[4], sA0[4], sA1[4];                                  \
        bf16x4 pfB0[4], pfB1[4], pfA0[4], pfA1[4];                               \
        __builtin_amdgcn_s_setprio(1);                                           \
        ZS(sB0)                                                                  \
        if (a0) { ZS(sA0) QKD(sB0, sA0, BUF, 0) } else { QK1(sB0, BUF, 0) }      \
        if (v1) {                                                                \
            ZS(sB1)                                                              \
            if (a1) { ZS(sA1) QKD(sB1, sA1, BUF, 1) } else { QK1(sB1, BUF, 1) }  \
        }                                                                        \
        __builtin_amdgcn_s_setprio(0);                                           \
        if (kt0 == qtB) { MASKD(sB0) }                                           \
        if (v1 && kt1 == qtB) { MASKD(sB1) }                                     \
        if (a0 && kt0 == qtA) { MASKD(sA0) }                                     \
        if (a1 && kt1 == qtA) { MASKD(sA1) }                                     \
        softmax_step(sB0, mB, llB, oB, pfB0);                                    \
        PVG(oB, pfB0, BUF, 0)                                                    \
        if (v1) { softmax_step(sB1, mB, llB, oB, pfB1); PVG(oB, pfB1, BUF, 1) }  \
        if (a0) { softmax_step(sA0, mA, llA, oA, pfA0); PVG(oA, pfA0, BUF, 0) }  \
        if (a1) { softmax_step(sA1, mA, llA, oA, pfA1); PVG(oA, pfA1, BUF, 1) }  \
    }

    const int NT = (qtB + 2) >> 1;          // ceil((qtB+1)/2), 9..16
    STAGE(0, 0)

    int i = 0;
    for (; i + 1 < NT; i += 2) {
        ITER(0, i)
        ITER(1, i + 1)
    }
    if (i < NT) ITER(0, i)
#undef ITER
#undef PVG
#undef MASKD
#undef QK1
#undef QKD
#undef ZS
#undef STAGE

    // epilogue: deferred cross-lane l reduction (once), then normalize + store
    {
        float lB = llB;
        lB += __shfl_xor(lB, 16);
        lB += __shfl_xor(lB, 32);
        const float inv = 1.0f / lB;
        const int t = q0B + l16;
        #pragma unroll
        for (int db = 0; db < 4; db++) {
            union { ushort4 w; unsigned u[2]; } ou;
            ou.u[0] = pkbf(oB[db][0] * inv, oB[db][1] * inv);
            ou.u[1] = pkbf(oB[db][2] * inv, oB[db][3] * inv);
            *(ushort4*)(Oout + (((size_t)b * T_SEQ + t) * NH + h) * HD + db * 16 + quad * 4) = ou.w;
        }
    }
    {
        float lA = llA;
        lA += __shfl_xor(lA, 16);
        lA += __shfl_xor(lA, 32);
        const float inv = 1.0f / lA;
        const int t = q0A + l16;
        #pragma unroll
        for (int db = 0; db < 4; db++) {
            union { ushort4 w; unsigned u[2]; } ou;
            ou.u[0] = pkbf(oA[db][0] * inv, oA[db][1] * inv);
            ou.u[1] = pkbf(oA[db][2] * inv, oA[db][3] * inv);
            *(ushort4*)(Oout + (((size_t)b * T_SEQ + t) * NH + h) * HD + db * 16 + quad * 4) = ou.w;
        }
    }
}

extern "C" void kernel_launch(void* const* d_in, const int* in_sizes, int n_in,
                              void* d_out, int out_size, void* d_ws, size_t ws_size,
                              hipStream_t stream) {
    const float* x    = (const float*)d_in[0];   // [2,2048,1024] fp32
    const float* Wqkv = (const float*)d_in[1];   // [1024,3072]  fp32
    const float* Wout = (const float*)d_in[2];   // [1024,1024]  fp32
    ushort* ws = (ushort*)d_ws;

    ushort* wt_qkv = ws;                               // bf16 [3072][1024]
    ushort* wt_out = wt_qkv + 3072 * 1024;             // bf16 [1024][1024]
    ushort* q_ws   = wt_out + 1024 * 1024;             // bf16 [B,H,T,hd] (pre-scaled)
    ushort* k_ws   = q_ws + 4194304;
    ushort* v_t    = k_ws + 4194304;                   // bf16 [B,H,hd,T]
    ushort* a_out  = v_t + 4194304;                    // bf16 [B,T,C]
    ushort* x_bf   = a_out + 4194304;                  // bf16 [B,T,C]

    prep_kernel<<<dim3(6144), 256, 0, stream>>>(Wqkv, Wout, x, wt_qkv, wt_out, x_bf);

    gemm_bt<0, 128><<<dim3(32, 24), 256, 0, stream>>>(x_bf, wt_qkv, q_ws, k_ws, v_t,
                                                      4096, 3072, 1024);

    attn_kernel<<<dim3(512), 256, 0, stream>>>(q_ws, k_ws, v_t, a_out);

    gemm_bt<1, 64><<<dim3(32, 16), 256, 0, stream>>>(a_out, wt_out, (float*)d_out, nullptr, nullptr,
                                                     4096, 1024, 1024);
}

// Round 8
// 170.115 us; speedup vs baseline: 1.0410x; 1.0410x over previous
//
#include <hip/hip_runtime.h>
#include <hip/hip_bf16.h>

typedef __attribute__((ext_vector_type(8))) short short8;
typedef __attribute__((ext_vector_type(4))) short bf16x4;
typedef __attribute__((ext_vector_type(4))) float floatx4;

#define T_SEQ 2048
#define NH    16
#define HD    64
#define QSCALE 0.18033688f   // 0.125 * log2(e): folded into Q at GEMM1 epilogue

// v_mfma_f32_16x16x16_bf16 (4 bf16/lane A,B; 4 f32/lane C)
#define MFMA16(a, b, c) __builtin_amdgcn_mfma_f32_16x16x16bf16_1k(a, b, c, 0, 0, 0)
#define MFMA32(a, b, c) __builtin_amdgcn_mfma_f32_16x16x32_bf16(a, b, c, 0, 0, 0)

__device__ __forceinline__ ushort f2bf(float f) {
    union { float f; unsigned u; } un; un.f = f;
    unsigned r = un.u + 0x7fff + ((un.u >> 16) & 1);
    return (ushort)(r >> 16);
}
__device__ __forceinline__ unsigned pkbf(float a, float b) {   // packed cvt (1 inst)
    __hip_bfloat162 t = __float22bfloat162_rn(float2{a, b});
    return *reinterpret_cast<unsigned*>(&t);
}

typedef const __attribute__((address_space(1))) unsigned int* gp1_t;
typedef __attribute__((address_space(3))) unsigned int* lp3_t;
__device__ __forceinline__ void gl_lds16(const ushort* g, ushort* l) {
    __builtin_amdgcn_global_load_lds((gp1_t)g, (lp3_t)l, 16, 0, 0);
}

// -------- fused prep: W transposes (fp32->bf16) + x convert ----------------
__global__ void prep_kernel(const float* __restrict__ Wqkv, const float* __restrict__ Wout,
                            const float* __restrict__ x, ushort* __restrict__ wt_qkv,
                            ushort* __restrict__ wt_out, ushort* __restrict__ x_bf) {
    __shared__ ushort tile[32][33];
    const int bid = blockIdx.x;
    if (bid >= 4096) {   // convert path
        size_t i = ((size_t)(bid - 4096) * 256 + threadIdx.x) * 8;
        float4 f0 = *(const float4*)(x + i);
        float4 f1 = *(const float4*)(x + i + 4);
        short8 v;
        v[0] = (short)f2bf(f0.x); v[1] = (short)f2bf(f0.y);
        v[2] = (short)f2bf(f0.z); v[3] = (short)f2bf(f0.w);
        v[4] = (short)f2bf(f1.x); v[5] = (short)f2bf(f1.y);
        v[6] = (short)f2bf(f1.z); v[7] = (short)f2bf(f1.w);
        *(short8*)(x_bf + i) = v;
        return;
    }
    const float* in; ushort* out; int R, C, gx, gy;
    if (bid < 3072) { in = Wqkv; out = wt_qkv; R = 1024; C = 3072; gx = bid % 96; gy = bid / 96; }
    else            { int t = bid - 3072; in = Wout; out = wt_out; R = 1024; C = 1024; gx = t & 31; gy = t >> 5; }
    const int tx = threadIdx.x & 31, ty = threadIdx.x >> 5;
    const int bx = gx * 32, by = gy * 32;
    #pragma unroll
    for (int i = ty; i < 32; i += 8)
        tile[i][tx] = f2bf(in[(size_t)(by + i) * C + bx + tx]);
    __syncthreads();
    #pragma unroll
    for (int i = ty; i < 32; i += 8)
        out[(size_t)(bx + i) * R + by + tx] = tile[tx][i];
}

// ---------------- GEMM: C[M][N] = A[M][K] * Bt[N][K]^T  (bf16 MFMA, fp32 acc) --
// Tile 128 x BN. BK=64. launch_bounds(256,3): VGPR cap ~170 -> 3 blocks/CU so
// the per-K-step barrier+vmcnt drain overlaps with 2 co-resident blocks (m114
// mechanism; m97 ran at ~3/CU). XOR-swizzled staging; XCD bijective swizzle.
// EPI==0 epilogues (Q/K scatter and V transpose) go through LDS for coalesced
// 16B stores.
template <int EPI, int BN>
__global__ __launch_bounds__(256, 3)
void gemm_bt(const ushort* __restrict__ A, const ushort* __restrict__ Bt,
             void* __restrict__ O0, ushort* __restrict__ O1, ushort* __restrict__ O2,
             int M, int N, int K) {
    constexpr int NJ = BN / 32;                    // j-frags per wave (BN/2/16)
    constexpr int NB = (BN * 8) / 256;             // B staging chunks per thread
    __shared__ __align__(16) ushort smem[8192 + BN * 64];   // As | Bs; epilogue reuse
    ushort* As = smem;
    ushort* Bs = smem + 8192;
    const int tid  = threadIdx.x;
    const int wave = tid >> 6, lane = tid & 63;
    const int quad = lane >> 4, l16 = lane & 15;
    const int wm = (wave >> 1) * 64, wn = (wave & 1) * (BN / 2);

    const int nwg = gridDim.x * gridDim.y;            // multiple of 8
    const int lid = blockIdx.y * gridDim.x + blockIdx.x;
    const int cpx = nwg >> 3;
    const int swz = (lid & 7) * cpx + (lid >> 3);
    const int m0 = (swz / gridDim.y) * 128;
    const int n0 = (swz % gridDim.y) * BN;

    // staging pointers: A 1024 chunks (4/thread), B BN*8 chunks (NB/thread)
    const ushort* aP[4];
    const ushort* bP[NB];
    #pragma unroll
    for (int j = 0; j < 4; j++) {
        int c = tid + j * 256;
        int r = c >> 3;
        int g = ((c & 7) ^ (r & 7)) * 8;
        aP[j] = A + (size_t)(m0 + r) * K + g;
    }
    #pragma unroll
    for (int j = 0; j < NB; j++) {
        int c = tid + j * 256;
        int r = c >> 3;
        int g = ((c & 7) ^ (r & 7)) * 8;
        bP[j] = Bt + (size_t)(n0 + r) * K + g;
    }

    floatx4 acc[4][NJ];
    #pragma unroll
    for (int i = 0; i < 4; i++)
        #pragma unroll
        for (int j = 0; j < NJ; j++)
            acc[i][j] = (floatx4){0.f, 0.f, 0.f, 0.f};

    const int xsw = l16 & 7;

    for (int k0 = 0; k0 < K; k0 += 64) {
        __syncthreads();
        #pragma unroll
        for (int j = 0; j < 4; j++)  gl_lds16(aP[j] + k0, &As[(tid + j * 256) * 8]);
        #pragma unroll
        for (int j = 0; j < NB; j++) gl_lds16(bP[j] + k0, &Bs[(tid + j * 256) * 8]);
        __syncthreads();
        #pragma unroll
        for (int kk = 0; kk < 2; kk++) {
            short8 af[4], bf[NJ];
            #pragma unroll
            for (int i = 0; i < 4; i++)
                af[i] = *(const short8*)(&As[(wm + i * 16 + l16) * 64 + ((kk * 4 + quad) ^ xsw) * 8]);
            #pragma unroll
            for (int j = 0; j < NJ; j++)
                bf[j] = *(const short8*)(&Bs[(wn + j * 16 + l16) * 64 + ((kk * 4 + quad) ^ xsw) * 8]);
            #pragma unroll
            for (int i = 0; i < 4; i++)
                #pragma unroll
                for (int j = 0; j < NJ; j++)
                    acc[i][j] = MFMA32(af[i], bf[j], acc[i][j]);
        }
    }

    if constexpr (EPI == 0) {
        const int b = m0 >> 11;
        const int t0 = m0 & 2047;
        if (n0 >= 2048) {
            // pure V block: LDS transpose -> coalesced 16B stores into vT[B,H,hd,T]
            const int head0 = (n0 - 2048) >> 6;
            __syncthreads();
            #pragma unroll
            for (int nh = 0; nh < 2; nh++) {
                if ((wave & 1) == nh) {
                    #pragma unroll
                    for (int j = 0; j < NJ; j++)
                        #pragma unroll
                        for (int i = 0; i < 4; i++) {
                            int nl = j * 16 + l16;
                            int mB = wm + i * 16 + quad * 4;
                            *(unsigned*)(&smem[nl * 136 + mB])     = pkbf(acc[i][j][0], acc[i][j][1]);
                            *(unsigned*)(&smem[nl * 136 + mB + 2]) = pkbf(acc[i][j][2], acc[i][j][3]);
                        }
                }
                __syncthreads();
                #pragma unroll
                for (int cc = 0; cc < 4; cc++) {
                    int c = cc * 256 + tid;
                    int row = c >> 4, mcol = (c & 15) * 8;
                    uint4 v = *(const uint4*)(&smem[row * 136 + mcol]);
                    *(uint4*)(&O2[((size_t)(b * NH + head0 + nh) * HD + row) * T_SEQ + t0 + mcol]) = v;
                }
                __syncthreads();
            }
        } else {
            // Q/K block: LDS transpose -> coalesced 16B stores into [B,H,T,hd].
            __syncthreads();
            #pragma unroll
            for (int nh = 0; nh < 2; nh++) {
                const int nn = n0 + nh * 64;
                const int part = nn >> 10;                 // 0 = Q, 1 = K
                const int head = (nn & 1023) >> 6;
                ushort* OP = (part == 0) ? (ushort*)O0 : O1;
                const float qs = (part == 0) ? QSCALE : 1.0f;
                if ((wave & 1) == nh) {
                    #pragma unroll
                    for (int i = 0; i < 4; i++)
                        #pragma unroll
                        for (int j = 0; j < NJ; j++) {
                            const int col = j * 16 + l16;
                            const int rowb = wm + i * 16 + quad * 4;
                            #pragma unroll
                            for (int r = 0; r < 4; r++)
                                smem[(rowb + r) * 72 + col] = f2bf(acc[i][j][r] * qs);
                        }
                }
                __syncthreads();
                const size_t obase = ((size_t)(b * NH + head)) * T_SEQ + t0;
                #pragma unroll
                for (int cc = 0; cc < 4; cc++) {
                    int c = cc * 256 + tid;
                    int row = c >> 3, col8 = (c & 7) * 8;
                    uint4 v = *(const uint4*)(&smem[row * 72 + col8]);
                    *(uint4*)(&OP[(obase + row) * HD + col8]) = v;
                }
                __syncthreads();
            }
        }
        return;
    } else {
        #pragma unroll
        for (int i = 0; i < 4; i++)
            #pragma unroll
            for (int j = 0; j < NJ; j++)
                #pragma unroll
                for (int r = 0; r < 4; r++) {
                    int m = m0 + wm + i * 16 + quad * 4 + r;
                    int n = n0 + wn + j * 16 + l16;
                    ((float*)O0)[(size_t)m * N + n] = acc[i][j][r];
                }
    }
}

// -------- online-softmax over one 64-key S^T tile: ALL-DEFERRED version --------
// No cross-lane ops on the common path: per-lane max vote (T13, thr=8 in log2
// domain); lane-local partial l (rescaled by alpha like O, reduced once in the
// epilogue). Cross-lane max (2 shfl) only on the rare rescale-trigger path.
__device__ __forceinline__ void softmax_step(floatx4 s[4], float& mst, float& ll,
                                             floatx4 o[4], bf16x4 pf[4]) {
    float t0 = fmaxf(fmaxf(s[0][0], s[0][1]), fmaxf(s[0][2], s[0][3]));
    float t1 = fmaxf(fmaxf(s[1][0], s[1][1]), fmaxf(s[1][2], s[1][3]));
    float t2 = fmaxf(fmaxf(s[2][0], s[2][1]), fmaxf(s[2][2], s[2][3]));
    float t3 = fmaxf(fmaxf(s[3][0], s[3][1]), fmaxf(s[3][2], s[3][3]));
    float t  = fmaxf(fmaxf(t0, t1), fmaxf(t2, t3));
    if (!__all(t - mst <= 8.0f)) {      // rare: some lane's max really grew
        t = fmaxf(t, __shfl_xor(t, 16));
        t = fmaxf(t, __shfl_xor(t, 32));
        float mnew  = fmaxf(mst, t);
        float alpha = exp2f(mst - mnew);
        mst = mnew;
        ll  *= alpha;
        #pragma unroll
        for (int db = 0; db < 4; db++)
            #pragma unroll
            for (int r = 0; r < 4; r++) o[db][r] *= alpha;
    }
    #pragma unroll
    for (int j = 0; j < 4; j++) {
        float p0 = exp2f(s[j][0] - mst);
        float p1 = exp2f(s[j][1] - mst);
        float p2 = exp2f(s[j][2] - mst);
        float p3 = exp2f(s[j][3] - mst);
        ll += (p0 + p1) + (p2 + p3);
        union { bf16x4 v; unsigned u[2]; } pu;
        pu.u[0] = pkbf(p0, p1);
        pu.u[1] = pkbf(p2, p3);
        pf[j] = pu.v;
    }
}

// ---------------- flash attention, S^T formulation, folded q-tile pairs -------
// Block = (bh, pair): q-tiles {p, 31-p}, uniform 33 subtile-computes per block.
// R3 schedule (best measured): both 64-key subtiles of a staged 128-key chunk
// run as concurrent chains; QK MFMAs up front, softmax(next) adjacent to
// PV(prev). One barrier per 128 keys. All-deferred softmax.
__global__ __launch_bounds__(256, 2)
void attn_kernel(const ushort* __restrict__ Q, const ushort* __restrict__ Kk,
                 const ushort* __restrict__ Vt, ushort* __restrict__ Oout) {
    __shared__ __align__(16) ushort Ks[2][128 * 64];   // [key][d]
    __shared__ __align__(16) ushort Vs[2][64 * 128];   // [d][key]
    const int tid  = threadIdx.x;
    const int wave = tid >> 6, lane = tid & 63;
    const int quad = lane >> 4, l16 = lane & 15;
    const int idx = blockIdx.x;
    const int bh = idx & 31;
    const int jp = idx >> 5;                         // 0..15
    const int p  = (jp < 8) ? jp : (15 - (jp - 8));  // co-res {jp,jp+8} -> {p,15-p}
    const int qtA = p, qtB = 31 - p;                 // qtA <= 15 < 16 <= qtB
    const int b = bh >> 4, h = bh & 15;

    const ushort* qp = Q  + (size_t)bh * T_SEQ * HD;
    const ushort* kp = Kk + (size_t)bh * T_SEQ * HD;
    const ushort* vp = Vt + (size_t)bh * HD * T_SEQ;

    const int q0A = qtA * 64 + wave * 16;
    const int q0B = qtB * 64 + wave * 16;

    short8 qfA[2], qfB[2];                   // B-operand: n=q=l16, k=d
    #pragma unroll
    for (int kb = 0; kb < 2; kb++) {
        qfA[kb] = *(const short8*)(qp + (size_t)(q0A + l16) * HD + kb * 32 + quad * 8);
        qfB[kb] = *(const short8*)(qp + (size_t)(q0B + l16) * HD + kb * 32 + quad * 8);
    }

    floatx4 oA[4], oB[4];                    // O^T accum: d = db*16+quad*4+r, q = l16
    #pragma unroll
    for (int db = 0; db < 4; db++) {
        oA[db] = (floatx4){0.f, 0.f, 0.f, 0.f};
        oB[db] = (floatx4){0.f, 0.f, 0.f, 0.f};
    }
    float mA = -1e30f, llA = 0.f, mB = -1e30f, llB = 0.f;

    // staging offsets: 1024 chunks of 16B per operand per 128-key chunk;
    // thread covers c = tid + j*256. Pre-swizzled global source so the
    // (linear) gl_lds destination yields XOR-swizzled LDS rows.
    int koff[4], voff[4];
    #pragma unroll
    for (int j = 0; j < 4; j++) {
        int c = tid + j * 256;
        int kr = c >> 3;                       // 0..127 (key)
        koff[j] = kr * HD + (((c & 7) ^ (kr & 7)) * 8);
        int vr = c >> 4;                       // 0..63 (d)
        voff[j] = vr * T_SEQ + ((((c & 15) ^ (vr & 7))) * 8);
    }

#define STAGE(BUF, I)                                                            \
    {                                                                            \
        const ushort* kg = kp + (size_t)(I) * 128 * HD;                          \
        const ushort* vg = vp + (I) * 128;                                       \
        gl_lds16(kg + koff[0], &Ks[BUF][(tid      ) * 8]);                       \
        gl_lds16(kg + koff[1], &Ks[BUF][(tid + 256) * 8]);                       \
        gl_lds16(kg + koff[2], &Ks[BUF][(tid + 512) * 8]);                       \
        gl_lds16(kg + koff[3], &Ks[BUF][(tid + 768) * 8]);                       \
        gl_lds16(vg + voff[0], &Vs[BUF][(tid      ) * 8]);                       \
        gl_lds16(vg + voff[1], &Vs[BUF][(tid + 256) * 8]);                       \
        gl_lds16(vg + voff[2], &Vs[BUF][(tid + 512) * 8]);                       \
        gl_lds16(vg + voff[3], &Vs[BUF][(tid + 768) * 8]);                       \
    }

    // hoisted LDS fragment addresses (ushort indices)
    const int xsw = (l16 & 7), qh = quad >> 1, ql = quad & 1;
    const int ka0 = l16 * 64 + ((quad ^ xsw) * 8);          // K: row stride 64
    const int ka1 = l16 * 64 + (((4 + quad) ^ xsw) * 8);
    int va[4];                                               // V: row stride 128
    #pragma unroll
    for (int jj = 0; jj < 4; jj++)
        va[jj] = l16 * 128 + (((2 * jj + qh) ^ xsw) * 8) + ql * 4;

#define ZS(S) { _Pragma("unroll") for (int z = 0; z < 4; z++) S[z] = (floatx4){0.f, 0.f, 0.f, 0.f}; }

// dual QK: one kf LDS read feeds both tiles' accumulations
#define QKD(SB, SA, BUF, ST)                                                     \
    {                                                                            \
        _Pragma("unroll")                                                        \
        for (int jj = 0; jj < 4; jj++) {                                         \
            short8 kf = *(const short8*)(&Ks[BUF][(ST) * 4096 + jj * 1024 + ka0]); \
            SB[jj] = MFMA32(kf, qfB[0], SB[jj]);                                 \
            SA[jj] = MFMA32(kf, qfA[0], SA[jj]);                                 \
        }                                                                        \
        _Pragma("unroll")                                                        \
        for (int jj = 0; jj < 4; jj++) {                                         \
            short8 kf = *(const short8*)(&Ks[BUF][(ST) * 4096 + jj * 1024 + ka1]); \
            SB[jj] = MFMA32(kf, qfB[1], SB[jj]);                                 \
            SA[jj] = MFMA32(kf, qfA[1], SA[jj]);                                 \
        }                                                                        \
    }

#define QK1(SB, BUF, ST)                                                         \
    {                                                                            \
        _Pragma("unroll")                                                        \
        for (int jj = 0; jj < 4; jj++) {                                         \
            short8 kf = *(const short8*)(&Ks[BUF][(ST) * 4096 + jj * 1024 + ka0]); \
            SB[jj] = MFMA32(kf, qfB[0], SB[jj]);                                 \
        }                                                                        \
        _Pragma("unroll")                                                        \
        for (int jj = 0; jj < 4; jj++) {                                         \
            short8 kf = *(const short8*)(&Ks[BUF][(ST) * 4096 + jj * 1024 + ka1]); \
            SB[jj] = MFMA32(kf, qfB[1], SB[jj]);                                 \
        }                                                                        \
    }

#define MASKD(S)                                                                 \
    {                                                                            \
        _Pragma("unroll")                                                        \
        for (int jj = 0; jj < 4; jj++)                                           \
            _Pragma("unroll")                                                    \
            for (int rr = 0; rr < 4; rr++)                                       \
                if (jj * 16 + quad * 4 + rr > wave * 16 + l16) S[jj][rr] = -1e30f; \
    }

#define PVG(O, PF, BUF, ST)                                                      \
    {                                                                            \
        _Pragma("unroll")                                                        \
        for (int jj = 0; jj < 4; jj++)                                           \
            _Pragma("unroll")                                                    \
            for (int db = 0; db < 4; db++) {                                     \
                bf16x4 vf = *(const bf16x4*)(&Vs[BUF][va[jj] + (ST) * 64 + db * 2048]); \
                O[db] = MFMA16(vf, PF[jj], O[db]);                               \
            }                                                                    \
    }

// one 128-key iteration: barrier (drains prefetch), prefetch next chunk,
// then both 64-key subtiles as interleaved chains:
//   QK(all) -> smB0 -> [PV B0 || smB1] -> [PV B1 || smA0] -> [PV A0 || smA1] -> PV A1
#define ITER(BUF, I)                                                             \
    {                                                                            \
        __syncthreads();                                                         \
        if ((I) + 1 < NT) STAGE((BUF) ^ 1, (I) + 1)                              \
        const int kt0 = 2 * (I), kt1 = kt0 + 1;                                  \
        const bool v1 = (kt1 <= qtB);                                            \
        const bool a0 = (kt0 <= qtA), a1 = (kt1 <= qtA);                         \
        floatx4 sB0[4], sB1[4], sA0[4], sA1[4];                                  \
        bf16x4 pfB0[4], pfB1[4], pfA0[4], pfA1[4];                               \
        __builtin_amdgcn_s_setprio(1);                                           \
        ZS(sB0)                                                                  \
        if (a0) { ZS(sA0) QKD(sB0, sA0, BUF, 0) } else { QK1(sB0, BUF, 0) }      \
        if (v1) {                                                                \
            ZS(sB1)                                                              \
            if (a1) { ZS(sA1) QKD(sB1, sA1, BUF, 1) } else { QK1(sB1, BUF, 1) }  \
        }                                                                        \
        __builtin_amdgcn_s_setprio(0);                                           \
        if (kt0 == qtB) { MASKD(sB0) }                                           \
        if (v1 && kt1 == qtB) { MASKD(sB1) }                                     \
        if (a0 && kt0 == qtA) { MASKD(sA0) }                                     \
        if (a1 && kt1 == qtA) { MASKD(sA1) }                                     \
        softmax_step(sB0, mB, llB, oB, pfB0);                                    \
        PVG(oB, pfB0, BUF, 0)                                                    \
        if (v1) { softmax_step(sB1, mB, llB, oB, pfB1); PVG(oB, pfB1, BUF, 1) }  \
        if (a0) { softmax_step(sA0, mA, llA, oA, pfA0); PVG(oA, pfA0, BUF, 0) }  \
        if (a1) { softmax_step(sA1, mA, llA, oA, pfA1); PVG(oA, pfA1, BUF, 1) }  \
    }

    const int NT = (qtB + 2) >> 1;          // ceil((qtB+1)/2), 9..16
    STAGE(0, 0)

    int i = 0;
    for (; i + 1 < NT; i += 2) {
        ITER(0, i)
        ITER(1, i + 1)
    }
    if (i < NT) ITER(0, i)
#undef ITER
#undef PVG
#undef MASKD
#undef QK1
#undef QKD
#undef ZS
#undef STAGE

    // epilogue: deferred cross-lane l reduction (once), then normalize + store
    {
        float lB = llB;
        lB += __shfl_xor(lB, 16);
        lB += __shfl_xor(lB, 32);
        const float inv = 1.0f / lB;
        const int t = q0B + l16;
        #pragma unroll
        for (int db = 0; db < 4; db++) {
            union { ushort4 w; unsigned u[2]; } ou;
            ou.u[0] = pkbf(oB[db][0] * inv, oB[db][1] * inv);
            ou.u[1] = pkbf(oB[db][2] * inv, oB[db][3] * inv);
            *(ushort4*)(Oout + (((size_t)b * T_SEQ + t) * NH + h) * HD + db * 16 + quad * 4) = ou.w;
        }
    }
    {
        float lA = llA;
        lA += __shfl_xor(lA, 16);
        lA += __shfl_xor(lA, 32);
        const float inv = 1.0f / lA;
        const int t = q0A + l16;
        #pragma unroll
        for (int db = 0; db < 4; db++) {
            union { ushort4 w; unsigned u[2]; } ou;
            ou.u[0] = pkbf(oA[db][0] * inv, oA[db][1] * inv);
            ou.u[1] = pkbf(oA[db][2] * inv, oA[db][3] * inv);
            *(ushort4*)(Oout + (((size_t)b * T_SEQ + t) * NH + h) * HD + db * 16 + quad * 4) = ou.w;
        }
    }
}

extern "C" void kernel_launch(void* const* d_in, const int* in_sizes, int n_in,
                              void* d_out, int out_size, void* d_ws, size_t ws_size,
                              hipStream_t stream) {
    const float* x    = (const float*)d_in[0];   // [2,2048,1024] fp32
    const float* Wqkv = (const float*)d_in[1];   // [1024,3072]  fp32
    const float* Wout = (const float*)d_in[2];   // [1024,1024]  fp32
    ushort* ws = (ushort*)d_ws;

    ushort* wt_qkv = ws;                               // bf16 [3072][1024]
    ushort* wt_out = wt_qkv + 3072 * 1024;             // bf16 [1024][1024]
    ushort* q_ws   = wt_out + 1024 * 1024;             // bf16 [B,H,T,hd] (pre-scaled)
    ushort* k_ws   = q_ws + 4194304;
    ushort* v_t    = k_ws + 4194304;                   // bf16 [B,H,hd,T]
    ushort* a_out  = v_t + 4194304;                    // bf16 [B,T,C]
    ushort* x_bf   = a_out + 4194304;                  // bf16 [B,T,C]

    prep_kernel<<<dim3(6144), 256, 0, stream>>>(Wqkv, Wout, x, wt_qkv, wt_out, x_bf);

    gemm_bt<0, 128><<<dim3(32, 24), 256, 0, stream>>>(x_bf, wt_qkv, q_ws, k_ws, v_t,
                                                      4096, 3072, 1024);

    attn_kernel<<<dim3(512), 256, 0, stream>>>(q_ws, k_ws, v_t, a_out);

    gemm_bt<1, 64><<<dim3(32, 16), 256, 0, stream>>>(a_out, wt_out, (float*)d_out, nullptr, nullptr,
                                                     4096, 1024, 1024);
}

// Round 10
// 166.781 us; speedup vs baseline: 1.0618x; 1.0200x over previous
//
#include <hip/hip_runtime.h>
#include <hip/hip_bf16.h>

typedef __attribute__((ext_vector_type(8))) short short8;
typedef __attribute__((ext_vector_type(4))) short bf16x4;
typedef __attribute__((ext_vector_type(4))) float floatx4;

#define T_SEQ 2048
#define NH    16
#define HD    64
#define QSCALE 0.18033688f   // 0.125 * log2(e): folded into Q at GEMM1 epilogue

// v_mfma_f32_16x16x16_bf16 (4 bf16/lane A,B; 4 f32/lane C)
#define MFMA16(a, b, c) __builtin_amdgcn_mfma_f32_16x16x16bf16_1k(a, b, c, 0, 0, 0)
#define MFMA32(a, b, c) __builtin_amdgcn_mfma_f32_16x16x32_bf16(a, b, c, 0, 0, 0)

__device__ __forceinline__ ushort f2bf(float f) {
    union { float f; unsigned u; } un; un.f = f;
    unsigned r = un.u + 0x7fff + ((un.u >> 16) & 1);
    return (ushort)(r >> 16);
}
__device__ __forceinline__ unsigned pkbf(float a, float b) {   // packed cvt (1 inst)
    __hip_bfloat162 t = __float22bfloat162_rn(float2{a, b});
    return *reinterpret_cast<unsigned*>(&t);
}

typedef const __attribute__((address_space(1))) unsigned int* gp1_t;
typedef __attribute__((address_space(3))) unsigned int* lp3_t;
__device__ __forceinline__ void gl_lds16(const ushort* g, ushort* l) {
    __builtin_amdgcn_global_load_lds((gp1_t)g, (lp3_t)l, 16, 0, 0);
}

// -------- fused prep: W transposes (fp32->bf16) + x convert ----------------
__global__ void prep_kernel(const float* __restrict__ Wqkv, const float* __restrict__ Wout,
                            const float* __restrict__ x, ushort* __restrict__ wt_qkv,
                            ushort* __restrict__ wt_out, ushort* __restrict__ x_bf) {
    __shared__ ushort tile[32][33];
    const int bid = blockIdx.x;
    if (bid >= 4096) {   // convert path
        size_t i = ((size_t)(bid - 4096) * 256 + threadIdx.x) * 8;
        float4 f0 = *(const float4*)(x + i);
        float4 f1 = *(const float4*)(x + i + 4);
        short8 v;
        v[0] = (short)f2bf(f0.x); v[1] = (short)f2bf(f0.y);
        v[2] = (short)f2bf(f0.z); v[3] = (short)f2bf(f0.w);
        v[4] = (short)f2bf(f1.x); v[5] = (short)f2bf(f1.y);
        v[6] = (short)f2bf(f1.z); v[7] = (short)f2bf(f1.w);
        *(short8*)(x_bf + i) = v;
        return;
    }
    const float* in; ushort* out; int R, C, gx, gy;
    if (bid < 3072) { in = Wqkv; out = wt_qkv; R = 1024; C = 3072; gx = bid % 96; gy = bid / 96; }
    else            { int t = bid - 3072; in = Wout; out = wt_out; R = 1024; C = 1024; gx = t & 31; gy = t >> 5; }
    const int tx = threadIdx.x & 31, ty = threadIdx.x >> 5;
    const int bx = gx * 32, by = gy * 32;
    #pragma unroll
    for (int i = ty; i < 32; i += 8)
        tile[i][tx] = f2bf(in[(size_t)(by + i) * C + bx + tx]);
    __syncthreads();
    #pragma unroll
    for (int i = ty; i < 32; i += 8)
        out[(size_t)(bx + i) * R + by + tx] = tile[tx][i];
}

// ---------------- GEMM: C[M][N] = A[M][K] * Bt[N][K]^T  (bf16 MFMA, fp32 acc) --
// Tile 128 x BN. BK=64. launch_bounds(256,3) -> 3 blocks/CU (R8 win).
// R9: square-ish XCD chunks (CM m-panels x CN n-panels per XCD) so the live
// working set fits the 4MB per-XCD L2. GEMM1: 8x12 -> A 2MB + B 3MB (was
// 4x24 -> A 1MB + B 6MB, B thrashed to L3). GEMM2: 4x16 (B 2MB already fits).
// XOR-swizzled staging; EPI==0 epilogues via LDS for coalesced 16B stores.
template <int EPI, int BN, int CM, int CN>
__global__ __launch_bounds__(256, 3)
void gemm_bt(const ushort* __restrict__ A, const ushort* __restrict__ Bt,
             void* __restrict__ O0, ushort* __restrict__ O1, ushort* __restrict__ O2,
             int M, int N, int K) {
    constexpr int NJ = BN / 32;                    // j-frags per wave (BN/2/16)
    constexpr int NB = (BN * 8) / 256;             // B staging chunks per thread
    __shared__ __align__(16) ushort smem[8192 + BN * 64];   // As | Bs; epilogue reuse
    ushort* As = smem;
    ushort* Bs = smem + 8192;
    const int tid  = threadIdx.x;
    const int wave = tid >> 6, lane = tid & 63;
    const int quad = lane >> 4, l16 = lane & 15;
    const int wm = (wave >> 1) * 64, wn = (wave & 1) * (BN / 2);

    // XCD-chunked bijective remap: xcd = dispatch-linear-id & 7 (HW round-robin);
    // each XCD owns a CM x CN panel chunk, n-fastest within.
    const int lid = blockIdx.y * gridDim.x + blockIdx.x;
    const int xcd = lid & 7, ib = lid >> 3;
    const int NGY = (int)gridDim.y / CN;           // n-groups across XCDs
    const int m0 = ((xcd / NGY) * CM + ib / CN) * 128;
    const int n0 = ((xcd % NGY) * CN + ib % CN) * BN;

    // staging pointers: A 1024 chunks (4/thread), B BN*8 chunks (NB/thread)
    const ushort* aP[4];
    const ushort* bP[NB];
    #pragma unroll
    for (int j = 0; j < 4; j++) {
        int c = tid + j * 256;
        int r = c >> 3;
        int g = ((c & 7) ^ (r & 7)) * 8;
        aP[j] = A + (size_t)(m0 + r) * K + g;
    }
    #pragma unroll
    for (int j = 0; j < NB; j++) {
        int c = tid + j * 256;
        int r = c >> 3;
        int g = ((c & 7) ^ (r & 7)) * 8;
        bP[j] = Bt + (size_t)(n0 + r) * K + g;
    }

    floatx4 acc[4][NJ];
    #pragma unroll
    for (int i = 0; i < 4; i++)
        #pragma unroll
        for (int j = 0; j < NJ; j++)
            acc[i][j] = (floatx4){0.f, 0.f, 0.f, 0.f};

    const int xsw = l16 & 7;

    for (int k0 = 0; k0 < K; k0 += 64) {
        __syncthreads();
        #pragma unroll
        for (int j = 0; j < 4; j++)  gl_lds16(aP[j] + k0, &As[(tid + j * 256) * 8]);
        #pragma unroll
        for (int j = 0; j < NB; j++) gl_lds16(bP[j] + k0, &Bs[(tid + j * 256) * 8]);
        __syncthreads();
        #pragma unroll
        for (int kk = 0; kk < 2; kk++) {
            short8 af[4], bf[NJ];
            #pragma unroll
            for (int i = 0; i < 4; i++)
                af[i] = *(const short8*)(&As[(wm + i * 16 + l16) * 64 + ((kk * 4 + quad) ^ xsw) * 8]);
            #pragma unroll
            for (int j = 0; j < NJ; j++)
                bf[j] = *(const short8*)(&Bs[(wn + j * 16 + l16) * 64 + ((kk * 4 + quad) ^ xsw) * 8]);
            #pragma unroll
            for (int i = 0; i < 4; i++)
                #pragma unroll
                for (int j = 0; j < NJ; j++)
                    acc[i][j] = MFMA32(af[i], bf[j], acc[i][j]);
        }
    }

    if constexpr (EPI == 0) {
        const int b = m0 >> 11;
        const int t0 = m0 & 2047;
        if (n0 >= 2048) {
            // pure V block: LDS transpose -> coalesced 16B stores into vT[B,H,hd,T]
            const int head0 = (n0 - 2048) >> 6;
            __syncthreads();
            #pragma unroll
            for (int nh = 0; nh < 2; nh++) {
                if ((wave & 1) == nh) {
                    #pragma unroll
                    for (int j = 0; j < NJ; j++)
                        #pragma unroll
                        for (int i = 0; i < 4; i++) {
                            int nl = j * 16 + l16;
                            int mB = wm + i * 16 + quad * 4;
                            *(unsigned*)(&smem[nl * 136 + mB])     = pkbf(acc[i][j][0], acc[i][j][1]);
                            *(unsigned*)(&smem[nl * 136 + mB + 2]) = pkbf(acc[i][j][2], acc[i][j][3]);
                        }
                }
                __syncthreads();
                #pragma unroll
                for (int cc = 0; cc < 4; cc++) {
                    int c = cc * 256 + tid;
                    int row = c >> 4, mcol = (c & 15) * 8;
                    uint4 v = *(const uint4*)(&smem[row * 136 + mcol]);
                    *(uint4*)(&O2[((size_t)(b * NH + head0 + nh) * HD + row) * T_SEQ + t0 + mcol]) = v;
                }
                __syncthreads();
            }
        } else {
            // Q/K block: LDS transpose -> coalesced 16B stores into [B,H,T,hd].
            __syncthreads();
            #pragma unroll
            for (int nh = 0; nh < 2; nh++) {
                const int nn = n0 + nh * 64;
                const int part = nn >> 10;                 // 0 = Q, 1 = K
                const int head = (nn & 1023) >> 6;
                ushort* OP = (part == 0) ? (ushort*)O0 : O1;
                const float qs = (part == 0) ? QSCALE : 1.0f;
                if ((wave & 1) == nh) {
                    #pragma unroll
                    for (int i = 0; i < 4; i++)
                        #pragma unroll
                        for (int j = 0; j < NJ; j++) {
                            const int col = j * 16 + l16;
                            const int rowb = wm + i * 16 + quad * 4;
                            #pragma unroll
                            for (int r = 0; r < 4; r++)
                                smem[(rowb + r) * 72 + col] = f2bf(acc[i][j][r] * qs);
                        }
                }
                __syncthreads();
                const size_t obase = ((size_t)(b * NH + head)) * T_SEQ + t0;
                #pragma unroll
                for (int cc = 0; cc < 4; cc++) {
                    int c = cc * 256 + tid;
                    int row = c >> 3, col8 = (c & 7) * 8;
                    uint4 v = *(const uint4*)(&smem[row * 72 + col8]);
                    *(uint4*)(&OP[(obase + row) * HD + col8]) = v;
                }
                __syncthreads();
            }
        }
        return;
    } else {
        #pragma unroll
        for (int i = 0; i < 4; i++)
            #pragma unroll
            for (int j = 0; j < NJ; j++)
                #pragma unroll
                for (int r = 0; r < 4; r++) {
                    int m = m0 + wm + i * 16 + quad * 4 + r;
                    int n = n0 + wn + j * 16 + l16;
                    ((float*)O0)[(size_t)m * N + n] = acc[i][j][r];
                }
    }
}

// -------- online-softmax over one 64-key S^T tile: ALL-DEFERRED version --------
// No cross-lane ops on the common path: per-lane max vote (T13, thr=8 in log2
// domain); lane-local partial l (rescaled by alpha like O, reduced once in the
// epilogue). Cross-lane max (2 shfl) only on the rare rescale-trigger path.
__device__ __forceinline__ void softmax_step(floatx4 s[4], float& mst, float& ll,
                                             floatx4 o[4], bf16x4 pf[4]) {
    float t0 = fmaxf(fmaxf(s[0][0], s[0][1]), fmaxf(s[0][2], s[0][3]));
    float t1 = fmaxf(fmaxf(s[1][0], s[1][1]), fmaxf(s[1][2], s[1][3]));
    float t2 = fmaxf(fmaxf(s[2][0], s[2][1]), fmaxf(s[2][2], s[2][3]));
    float t3 = fmaxf(fmaxf(s[3][0], s[3][1]), fmaxf(s[3][2], s[3][3]));
    float t  = fmaxf(fmaxf(t0, t1), fmaxf(t2, t3));
    if (!__all(t - mst <= 8.0f)) {      // rare: some lane's max really grew
        t = fmaxf(t, __shfl_xor(t, 16));
        t = fmaxf(t, __shfl_xor(t, 32));
        float mnew  = fmaxf(mst, t);
        float alpha = exp2f(mst - mnew);
        mst = mnew;
        ll  *= alpha;
        #pragma unroll
        for (int db = 0; db < 4; db++)
            #pragma unroll
            for (int r = 0; r < 4; r++) o[db][r] *= alpha;
    }
    #pragma unroll
    for (int j = 0; j < 4; j++) {
        float p0 = exp2f(s[j][0] - mst);
        float p1 = exp2f(s[j][1] - mst);
        float p2 = exp2f(s[j][2] - mst);
        float p3 = exp2f(s[j][3] - mst);
        ll += (p0 + p1) + (p2 + p3);
        union { bf16x4 v; unsigned u[2]; } pu;
        pu.u[0] = pkbf(p0, p1);
        pu.u[1] = pkbf(p2, p3);
        pf[j] = pu.v;
    }
}

// ---------------- flash attention, S^T formulation, folded q-tile pairs -------
// Block = (bh, pair): q-tiles {p, 31-p}, uniform 33 subtile-computes per block.
// R3 schedule (best measured): both 64-key subtiles of a staged 128-key chunk
// run as concurrent chains; QK MFMAs up front, softmax(next) adjacent to
// PV(prev). One barrier per 128 keys. All-deferred softmax.
__global__ __launch_bounds__(256, 2)
void attn_kernel(const ushort* __restrict__ Q, const ushort* __restrict__ Kk,
                 const ushort* __restrict__ Vt, ushort* __restrict__ Oout) {
    __shared__ __align__(16) ushort Ks[2][128 * 64];   // [key][d]
    __shared__ __align__(16) ushort Vs[2][64 * 128];   // [d][key]
    const int tid  = threadIdx.x;
    const int wave = tid >> 6, lane = tid & 63;
    const int quad = lane >> 4, l16 = lane & 15;
    const int idx = blockIdx.x;
    const int bh = idx & 31;
    const int jp = idx >> 5;                         // 0..15
    const int p  = (jp < 8) ? jp : (15 - (jp - 8));  // co-res {jp,jp+8} -> {p,15-p}
    const int qtA = p, qtB = 31 - p;                 // qtA <= 15 < 16 <= qtB
    const int b = bh >> 4, h = bh & 15;

    const ushort* qp = Q  + (size_t)bh * T_SEQ * HD;
    const ushort* kp = Kk + (size_t)bh * T_SEQ * HD;
    const ushort* vp = Vt + (size_t)bh * HD * T_SEQ;

    const int q0A = qtA * 64 + wave * 16;
    const int q0B = qtB * 64 + wave * 16;

    short8 qfA[2], qfB[2];                   // B-operand: n=q=l16, k=d
    #pragma unroll
    for (int kb = 0; kb < 2; kb++) {
        qfA[kb] = *(const short8*)(qp + (size_t)(q0A + l16) * HD + kb * 32 + quad * 8);
        qfB[kb] = *(const short8*)(qp + (size_t)(q0B + l16) * HD + kb * 32 + quad * 8);
    }

    floatx4 oA[4], oB[4];                    // O^T accum: d = db*16+quad*4+r, q = l16
    #pragma unroll
    for (int db = 0; db < 4; db++) {
        oA[db] = (floatx4){0.f, 0.f, 0.f, 0.f};
        oB[db] = (floatx4){0.f, 0.f, 0.f, 0.f};
    }
    float mA = -1e30f, llA = 0.f, mB = -1e30f, llB = 0.f;

    // staging offsets: 1024 chunks of 16B per operand per 128-key chunk;
    // thread covers c = tid + j*256. Pre-swizzled global source so the
    // (linear) gl_lds destination yields XOR-swizzled LDS rows.
    int koff[4], voff[4];
    #pragma unroll
    for (int j = 0; j < 4; j++) {
        int c = tid + j * 256;
        int kr = c >> 3;                       // 0..127 (key)
        koff[j] = kr * HD + (((c & 7) ^ (kr & 7)) * 8);
        int vr = c >> 4;                       // 0..63 (d)
        voff[j] = vr * T_SEQ + ((((c & 15) ^ (vr & 7))) * 8);
    }

#define STAGE(BUF, I)                                                            \
    {                                                                            \
        const ushort* kg = kp + (size_t)(I) * 128 * HD;                          \
        const ushort* vg = vp + (I) * 128;                                       \
        gl_lds16(kg + koff[0], &Ks[BUF][(tid      ) * 8]);                       \
        gl_lds16(kg + koff[1], &Ks[BUF][(tid + 256) * 8]);                       \
        gl_lds16(kg + koff[2], &Ks[BUF][(tid + 512) * 8]);                       \
        gl_lds16(kg + koff[3], &Ks[BUF][(tid + 768) * 8]);                       \
        gl_lds16(vg + voff[0], &Vs[BUF][(tid      ) * 8]);                       \
        gl_lds16(vg + voff[1], &Vs[BUF][(tid + 256) * 8]);                       \
        gl_lds16(vg + voff[2], &Vs[BUF][(tid + 512) * 8]);                       \
        gl_lds16(vg + voff[3], &Vs[BUF][(tid + 768) * 8]);                       \
    }

    // hoisted LDS fragment addresses (ushort indices)
    const int xsw = (l16 & 7), qh = quad >> 1, ql = quad & 1;
    const int ka0 = l16 * 64 + ((quad ^ xsw) * 8);          // K: row stride 64
    const int ka1 = l16 * 64 + (((4 + quad) ^ xsw) * 8);
    int va[4];                                               // V: row stride 128
    #pragma unroll
    for (int jj = 0; jj < 4; jj++)
        va[jj] = l16 * 128 + (((2 * jj + qh) ^ xsw) * 8) + ql * 4;

#define ZS(S) { _Pragma("unroll") for (int z = 0; z < 4; z++) S[z] = (floatx4){0.f, 0.f, 0.f, 0.f}; }

// dual QK: one kf LDS read feeds both tiles' accumulations
#define QKD(SB, SA, BUF, ST)                                                     \
    {                                                                            \
        _Pragma("unroll")                                                        \
        for (int jj = 0; jj < 4; jj++) {                                         \
            short8 kf = *(const short8*)(&Ks[BUF][(ST) * 4096 + jj * 1024 + ka0]); \
            SB[jj] = MFMA32(kf, qfB[0], SB[jj]);                                 \
            SA[jj] = MFMA32(kf, qfA[0], SA[jj]);                                 \
        }                                                                        \
        _Pragma("unroll")                                                        \
        for (int jj = 0; jj < 4; jj++) {                                         \
            short8 kf = *(const short8*)(&Ks[BUF][(ST) * 4096 + jj * 1024 + ka1]); \
            SB[jj] = MFMA32(kf, qfB[1], SB[jj]);                                 \
            SA[jj] = MFMA32(kf, qfA[1], SA[jj]);                                 \
        }                                                                        \
    }

#define QK1(SB, BUF, ST)                                                         \
    {                                                                            \
        _Pragma("unroll")                                                        \
        for (int jj = 0; jj < 4; jj++) {                                         \
            short8 kf = *(const short8*)(&Ks[BUF][(ST) * 4096 + jj * 1024 + ka0]); \
            SB[jj] = MFMA32(kf, qfB[0], SB[jj]);                                 \
        }                                                                        \
        _Pragma("unroll")                                                        \
        for (int jj = 0; jj < 4; jj++) {                                         \
            short8 kf = *(const short8*)(&Ks[BUF][(ST) * 4096 + jj * 1024 + ka1]); \
            SB[jj] = MFMA32(kf, qfB[1], SB[jj]);                                 \
        }                                                                        \
    }

#define MASKD(S)                                                                 \
    {                                                                            \
        _Pragma("unroll")                                                        \
        for (int jj = 0; jj < 4; jj++)                                           \
            _Pragma("unroll")                                                    \
            for (int rr = 0; rr < 4; rr++)                                       \
                if (jj * 16 + quad * 4 + rr > wave * 16 + l16) S[jj][rr] = -1e30f; \
    }

#define PVG(O, PF, BUF, ST)                                                      \
    {                                                                            \
        _Pragma("unroll")                                                        \
        for (int jj = 0; jj < 4; jj++)                                           \
            _Pragma("unroll")                                                    \
            for (int db = 0; db < 4; db++) {                                     \
                bf16x4 vf = *(const bf16x4*)(&Vs[BUF][va[jj] + (ST) * 64 + db * 2048]); \
                O[db] = MFMA16(vf, PF[jj], O[db]);                               \
            }                                                                    \
    }

// one 128-key iteration: barrier (drains prefetch), prefetch next chunk,
// then both 64-key subtiles as interleaved chains:
//   QK(all) -> smB0 -> [PV B0 || smB1] -> [PV B1 || smA0] -> [PV A0 || smA1] -> PV A1
#define ITER(BUF, I)                                                             \
    {                                                                            \
        __syncthreads();                                                         \
        if ((I) + 1 < NT) STAGE((BUF) ^ 1, (I) + 1)                              \
        const int kt0 = 2 * (I), kt1 = kt0 + 1;                                  \
        const bool v1 = (kt1 <= qtB);                                            \
        const bool a0 = (kt0 <= qtA), a1 = (kt1 <= qtA);                         \
        floatx4 sB0[4], sB1[4], sA0[4], sA1[4];                                  \
        bf16x4 pfB0[4], pfB1[4], pfA0[4], pfA1[4];                               \
        __builtin_amdgcn_s_setprio(1);                                           \
        ZS(sB0)                                                                  \
        if (a0) { ZS(sA0) QKD(sB0, sA0, BUF, 0) } else { QK1(sB0, BUF, 0) }      \
        if (v1) {                                                                \
            ZS(sB1)                                                              \
            if (a1) { ZS(sA1) QKD(sB1, sA1, BUF, 1) } else { QK1(sB1, BUF, 1) }  \
        }                                                                        \
        __builtin_amdgcn_s_setprio(0);                                           \
        if (kt0 == qtB) { MASKD(sB0) }                                           \
        if (v1 && kt1 == qtB) { MASKD(sB1) }                                     \
        if (a0 && kt0 == qtA) { MASKD(sA0) }                                     \
        if (a1 && kt1 == qtA) { MASKD(sA1) }                                     \
        softmax_step(sB0, mB, llB, oB, pfB0);                                    \
        PVG(oB, pfB0, BUF, 0)                                                    \
        if (v1) { softmax_step(sB1, mB, llB, oB, pfB1); PVG(oB, pfB1, BUF, 1) }  \
        if (a0) { softmax_step(sA0, mA, llA, oA, pfA0); PVG(oA, pfA0, BUF, 0) }  \
        if (a1) { softmax_step(sA1, mA, llA, oA, pfA1); PVG(oA, pfA1, BUF, 1) }  \
    }

    const int NT = (qtB + 2) >> 1;          // ceil((qtB+1)/2), 9..16
    STAGE(0, 0)

    int i = 0;
    for (; i + 1 < NT; i += 2) {
        ITER(0, i)
        ITER(1, i + 1)
    }
    if (i < NT) ITER(0, i)
#undef ITER
#undef PVG
#undef MASKD
#undef QK1
#undef QKD
#undef ZS
#undef STAGE

    // epilogue: deferred cross-lane l reduction (once), then normalize + store
    {
        float lB = llB;
        lB += __shfl_xor(lB, 16);
        lB += __shfl_xor(lB, 32);
        const float inv = 1.0f / lB;
        const int t = q0B + l16;
        #pragma unroll
        for (int db = 0; db < 4; db++) {
            union { ushort4 w; unsigned u[2]; } ou;
            ou.u[0] = pkbf(oB[db][0] * inv, oB[db][1] * inv);
            ou.u[1] = pkbf(oB[db][2] * inv, oB[db][3] * inv);
            *(ushort4*)(Oout + (((size_t)b * T_SEQ + t) * NH + h) * HD + db * 16 + quad * 4) = ou.w;
        }
    }
    {
        float lA = llA;
        lA += __shfl_xor(lA, 16);
        lA += __shfl_xor(lA, 32);
        const float inv = 1.0f / lA;
        const int t = q0A + l16;
        #pragma unroll
        for (int db = 0; db < 4; db++) {
            union { ushort4 w; unsigned u[2]; } ou;
            ou.u[0] = pkbf(oA[db][0] * inv, oA[db][1] * inv);
            ou.u[1] = pkbf(oA[db][2] * inv, oA[db][3] * inv);
            *(ushort4*)(Oout + (((size_t)b * T_SEQ + t) * NH + h) * HD + db * 16 + quad * 4) = ou.w;
        }
    }
}

extern "C" void kernel_launch(void* const* d_in, const int* in_sizes, int n_in,
                              void* d_out, int out_size, void* d_ws, size_t ws_size,
                              hipStream_t stream) {
    const float* x    = (const float*)d_in[0];   // [2,2048,1024] fp32
    const float* Wqkv = (const float*)d_in[1];   // [1024,3072]  fp32
    const float* Wout = (const float*)d_in[2];   // [1024,1024]  fp32
    ushort* ws = (ushort*)d_ws;

    ushort* wt_qkv = ws;                               // bf16 [3072][1024]
    ushort* wt_out = wt_qkv + 3072 * 1024;             // bf16 [1024][1024]
    ushort* q_ws   = wt_out + 1024 * 1024;             // bf16 [B,H,T,hd] (pre-scaled)
    ushort* k_ws   = q_ws + 4194304;
    ushort* v_t    = k_ws + 4194304;                   // bf16 [B,H,hd,T]
    ushort* a_out  = v_t + 4194304;                    // bf16 [B,T,C]
    ushort* x_bf   = a_out + 4194304;                  // bf16 [B,T,C]

    prep_kernel<<<dim3(6144), 256, 0, stream>>>(Wqkv, Wout, x, wt_qkv, wt_out, x_bf);

    // GEMM1: 768 blocks = 96/XCD, chunk 8m x 12n (A 2MB + B 3MB ~ L2-fit)
    gemm_bt<0, 128, 8, 12><<<dim3(32, 24), 256, 0, stream>>>(x_bf, wt_qkv, q_ws, k_ws, v_t,
                                                             4096, 3072, 1024);

    attn_kernel<<<dim3(512), 256, 0, stream>>>(q_ws, k_ws, v_t, a_out);

    // GEMM2: 512 blocks = 64/XCD, chunk 4m x 16n (B 2MB fully L2-fit)
    gemm_bt<1, 64, 4, 16><<<dim3(32, 16), 256, 0, stream>>>(a_out, wt_out, (float*)d_out,
                                                            nullptr, nullptr, 4096, 1024, 1024);
}